// Round 5
// baseline (1091.087 us; speedup 1.0000x reference)
//
#include <hip/hip_runtime.h>
#include <stdint.h>
#include <math.h>

// Match XLA-CPU's unfused mul/add on threshold-critical math.
#pragma clang fp contract(off)

#define NB    8
#define NPTS  2048
#define NS    1024
#define NG    30
#define NITER 10

typedef unsigned long long ull;

// ---------------- threefry2x32 (Random123 / JAX, 20 rounds) ----------------
__host__ __device__ __forceinline__ uint32_t rotl32(uint32_t x, int r){
  return (x << r) | (x >> (32 - r));
}
__host__ __device__ __forceinline__ void tf2x32(uint32_t k0, uint32_t k1,
                                                uint32_t x0, uint32_t x1,
                                                uint32_t& o0, uint32_t& o1){
  uint32_t k2 = k0 ^ k1 ^ 0x1BD11BDAu;
  x0 += k0; x1 += k1;
#define TFR(r) { x0 += x1; x1 = rotl32(x1, (r)); x1 ^= x0; }
  TFR(13) TFR(15) TFR(26) TFR(6)
  x0 += k1; x1 += k2 + 1u;
  TFR(17) TFR(29) TFR(16) TFR(24)
  x0 += k2; x1 += k0 + 2u;
  TFR(13) TFR(15) TFR(26) TFR(6)
  x0 += k0; x1 += k1 + 3u;
  TFR(17) TFR(29) TFR(16) TFR(24)
  x0 += k1; x1 += k2 + 4u;
  TFR(13) TFR(15) TFR(26) TFR(6)
  x0 += k2; x1 += k0 + 5u;
#undef TFR
  o0 = x0; o1 = x1;
}

// partitionable threefry: bits[e] = o0^o1 of tf(key,(0,e))
__device__ __forceinline__ uint32_t rand_bits(uint32_t k0, uint32_t k1, uint32_t e){
  uint32_t o0, o1; tf2x32(k0, k1, 0u, e, o0, o1);
  return o0 ^ o1;
}

// split(fold_in(key(42), it)): k_i = tf(folded, (0, i)), i in {0,1}
__device__ __forceinline__ void derive_key(int it, uint32_t which,
                                           uint32_t& a, uint32_t& b){
  uint32_t fa, fb;
  tf2x32(0u, 42u, 0u, (uint32_t)it, fa, fb);
  tf2x32(fa, fb, 0u, which, a, b);
}

// jax.random.uniform(minval=1e-9, maxval=1.0) -> gumbel  (monotone in bits' value)
__device__ __forceinline__ float gumbel_from(uint32_t bits){
  float f = __uint_as_float((bits >> 9) | 0x3f800000u) - 1.0f;  // [0,1)
  float u = fmaxf(1e-9f, f + 1e-9f);
  return -logf(-logf(u));
}

// ---------------- sort keys: (value desc, index asc) ----------------
__device__ __forceinline__ ull packkey(float v, uint32_t idx){
  uint32_t u = __float_as_uint(v);
  u = (u & 0x80000000u) ? ~u : (u | 0x80000000u);
  return ((ull)u << 32) | (ull)(0xFFFFFFFFu - idx);
}
__device__ __forceinline__ uint32_t unpackidx(ull k){
  return 0xFFFFFFFFu - (uint32_t)(k & 0xFFFFFFFFull);
}

__device__ __forceinline__ void bitonic_desc(ull* a, int M, int t, int T){
  for (int k = 2; k <= M; k <<= 1){
    for (int j = k >> 1; j > 0; j >>= 1){
      for (int i = t; i < M; i += T){
        int ixj = i ^ j;
        if (ixj > i){
          ull ai = a[i], aj = a[ixj];
          bool desc = ((i & k) == 0);
          if (desc ? (ai < aj) : (ai > aj)){ a[i] = aj; a[ixj] = ai; }
        }
      }
      __syncthreads();
    }
  }
}

// -------- wave-level (64-lane) register bitonic helpers, u64 keys --------
__device__ __forceinline__ ull shfl_xor_u64(ull x, int mask){
  return (ull)__shfl_xor((long long)x, mask, 64);
}

__device__ __forceinline__ ull sort32_desc(ull key, int l){
  int i = l & 31;
#pragma unroll
  for (int k = 2; k <= 16; k <<= 1){
#pragma unroll
    for (int j = k >> 1; j > 0; j >>= 1){
      ull other = shfl_xor_u64(key, j);
      bool up = ((l & j) == 0);
      bool take_max = (((i & k) == 0) == up);
      bool omax = other > key;
      key = (take_max == omax) ? other : key;
    }
  }
#pragma unroll
  for (int j = 16; j > 0; j >>= 1){
    ull other = shfl_xor_u64(key, j);
    bool up = ((l & j) == 0);
    bool omax = other > key;
    key = (up == omax) ? other : key;
  }
  return key;
}

__device__ __forceinline__ ull merge64_desc(ull key, int l){
#pragma unroll
  for (int j = 32; j > 0; j >>= 1){
    ull other = shfl_xor_u64(key, j);
    bool up = ((l & j) == 0);
    bool omax = other > key;
    key = (up == omax) ? other : key;
  }
  return key;
}

__device__ __forceinline__ ull mergehalves_desc(ull key, int l){
  ull rev = shfl_xor_u64(key, 31);
  if (l >= 32) key = rev;
  return merge64_desc(key, l);
}

// ---------------- kernel 0: nan/inf cleanup + softmax + log ----------------
__global__ __launch_bounds__(256) void ghv_softmax(const float* __restrict__ win,
                                                   float* __restrict__ w,
                                                   float* __restrict__ logw){
  int b = blockIdx.x, t = threadIdx.x;
  __shared__ float sh[NPTS];
  __shared__ float red[4];
  __shared__ float bcast;
  for (int n = t; n < NPTS; n += 256){
    float x = win[b*NPTS + n];
    if (isnan(x)) x = 1e-7f;
    if (isinf(x)) x = 1.0f;
    sh[n] = x;
  }
  __syncthreads();
  float m = -INFINITY;
  for (int n = t; n < NPTS; n += 256) m = fmaxf(m, sh[n]);
  for (int off = 32; off >= 1; off >>= 1) m = fmaxf(m, __shfl_down(m, off));
  if ((t & 63) == 0) red[t >> 6] = m;
  __syncthreads();
  if (t == 0) bcast = fmaxf(fmaxf(red[0], red[1]), fmaxf(red[2], red[3]));
  __syncthreads();
  float mx = bcast;
  float ss = 0.0f;
  for (int n = t; n < NPTS; n += 256){ float e = expf(sh[n] - mx); sh[n] = e; ss += e; }
  for (int off = 32; off >= 1; off >>= 1) ss += __shfl_down(ss, off);
  if ((t & 63) == 0) red[t >> 6] = ss;
  __syncthreads();
  if (t == 0) bcast = red[0] + red[1] + red[2] + red[3];
  __syncthreads();
  float tot = bcast;
  for (int n = t; n < NPTS; n += 256){
    float wv = sh[n] / tot;
    w[b*NPTS + n] = wv;
    logw[b*NPTS + n] = logf(wv);
  }
}

// ---------------- kernel 1: seed gumbel top-1024 + gather ----------------
__global__ __launch_bounds__(1024) void ghv_seed(const float* __restrict__ src,
                                                 const float* __restrict__ tgt,
                                                 const float* __restrict__ w,
                                                 const float* __restrict__ logw,
                                                 float* __restrict__ seeds,
                                                 int it0, int seq){
  __shared__ ull keys[NPTS];
  __shared__ uint32_t kk[2];
  int b = blockIdx.x, t = threadIdx.x;
  int it = it0 + blockIdx.z;
  int slot = seq ? 0 : it;
  if (t == 0){ derive_key(it, 0u, kk[0], kk[1]); }
  __syncthreads();
  uint32_t k0 = kk[0], k1 = kk[1];
  for (int n = t; n < NPTS; n += 1024){
    uint32_t bits = rand_bits(k0, k1, (uint32_t)(b*NPTS + n));
    float v = logw[b*NPTS + n] + gumbel_from(bits);
    keys[n] = packkey(v, (uint32_t)n);
  }
  __syncthreads();
  bitonic_desc(keys, NPTS, t, 1024);
  int s = t;
  uint32_t idx = unpackidx(keys[s]);
  const float* sb = src + b*3*NPTS;
  const float* tb = tgt + b*3*NPTS;
  float* sp = seeds + (size_t)slot*(NB*NS*8) + (size_t)((b << 10) + s) * 8;
  sp[0] = sb[idx]; sp[1] = sb[NPTS + idx]; sp[2] = sb[2*NPTS + idx];
  sp[3] = tb[idx]; sp[4] = tb[NPTS + idx]; sp[5] = tb[2*NPTS + idx];
  sp[6] = w[b*NPTS + idx]; sp[7] = 0.0f;
}

// ---------------- kernel 2: consensus + gumbel top-30 per (b,s) row ----------------
// Clip-aware: ~91% of elements have cons==0.1f exactly (shared base), so their
// key order == order of raw uniform bits. Exact v (logf/div/gumbel) is computed
// only for candidates = unclipped ∪ clipped-u-survivors (~30% of elements).
// grid (NS, NB, nz), block 512
__global__ __launch_bounds__(512) void ghv_nn(const float* __restrict__ seeds,
                                              unsigned short* __restrict__ nnb,
                                              int it0, int seq){
  __shared__ ull SH[1024];        // [cons f32 x1024 | ubits u32 x1024]; fallback: ull keys x1024
  __shared__ ull sbuf[256];
  __shared__ ull sbuf2[128];
  __shared__ float argls[512];    // phase1 arg list for unclipped candidates
  __shared__ unsigned short cand[512];
  __shared__ float red[8];
  __shared__ float srow[8];
  __shared__ float rowsum_sh;
  __shared__ uint32_t cmaxu[64];
  __shared__ uint32_t Tu_sh;
  __shared__ int ncand_sh, ovf_sh, ovf2_sh;
  __shared__ uint32_t kk[2];

  float* cons_sh = (float*)SH;
  uint32_t* ubits_sh = (uint32_t*)(SH + 512);

  int s = blockIdx.x, b = blockIdx.y, t = threadIdx.x;
  int it = it0 + blockIdx.z;
  int slot = seq ? 0 : it;
  const float* sdat = seeds + (size_t)slot*(NB*NS*8);
  size_t outoff = ((size_t)slot*(NB*NS) + (size_t)((b << 10) + s))*32;
  int wv = t >> 6, l = t & 63;

  if (t < 8) srow[t] = sdat[(size_t)((b << 10) + s)*8 + t];
  if (t == 0){ derive_key(it, 1u, kk[0], kk[1]); ncand_sh = 0; ovf_sh = 0; ovf2_sh = 0; }
  __syncthreads();
  uint32_t k0 = kk[0], k1 = kk[1];
  ull ltm = (l == 0) ? 0ull : ((1ull << l) - 1ull);

  // ---- phase 1: distances, classify, threefry bits; compact unclipped ----
  float argr[2]; bool unclip[2]; uint32_t bitsr[2];
#pragma unroll
  for (int q = 0; q < 2; ++q){
    int j = t + q*512;
    const float4* jp = (const float4*)(sdat + (size_t)((b << 10) + j)*8);
    float4 p0 = jp[0], p1 = jp[1];
    float dxs = srow[0]-p0.x, dys = srow[1]-p0.y, dzs = srow[2]-p0.z;
    float ds  = sqrtf(dxs*dxs + dys*dys + dzs*dzs);
    float dxc = srow[3]-p0.w, dyc = srow[4]-p1.x, dzc = srow[5]-p1.y;
    float dc  = sqrtf(dxc*dxc + dyc*dyc + dzc*dzc);
    float diff = ds - dc;
    float arg = (-(diff*diff)) / 0.01f;          // identical expression to ref
    argr[q] = arg;
    // conservative: arg < -2.3026f  =>  expf(arg) < 0.1 certainly => cons == 0.1f
    unclip[q] = !(arg < -2.3026f);
    uint32_t bits = rand_bits(k0, k1, (uint32_t)((b << 20) + (s << 10) + j));
    bitsr[q] = bits;
    ubits_sh[j] = bits;
    cons_sh[j] = 0.1f;
    ull bm = __ballot(unclip[q]);
    int cnt = __popcll(bm);
    int base = 0;
    if (l == 0) base = atomicAdd(&ncand_sh, cnt);
    base = __shfl(base, 0);
    if (unclip[q]){
      int pos = base + __popcll(bm & ltm);
      if (pos < 512){ cand[pos] = (unsigned short)j; argls[pos] = arg; }
      else ovf_sh = 1;
    }
  }
  __syncthreads();
  int n_u = ncand_sh;
  bool ovf = (ovf_sh != 0) || (n_u > 512);

  // ---- phase 2: exact cons (dense expf) ----
  if (!ovf){
    if (t < n_u){
      float c = fmaxf(expf(argls[t]), 0.1f);
      cons_sh[cand[t]] = c;
    }
  } else {
#pragma unroll
    for (int q = 0; q < 2; ++q){
      int j = t + q*512;
      if (unclip[q]) cons_sh[j] = fmaxf(expf(argr[q]), 0.1f);
    }
  }
  __syncthreads();

  // ---- phase 3: rowsum (identical summation tree to prior rounds) ----
  float part = cons_sh[t] + cons_sh[t + 512];
  for (int off = 32; off >= 1; off >>= 1) part += __shfl_down(part, off);
  if ((t & 63) == 0) red[t >> 6] = part;
  __syncthreads();
  if (t == 0){ float tot = 0.0f; for (int i = 0; i < 8; ++i) tot += red[i]; rowsum_sh = tot; }
  __syncthreads();
  float rowsum = rowsum_sh;

  // ---- phase 4: u-threshold over clipped, append survivors ----
  if (!ovf){
#pragma unroll
    for (int q = 0; q < 2; ++q){
      uint32_t m = unclip[q] ? 0u : bitsr[q];
#pragma unroll
      for (int d = 1; d <= 8; d <<= 1){
        uint32_t o = (uint32_t)__shfl_xor((int)m, d);
        m = (o > m) ? o : m;
      }
      if ((t & 15) == 0) cmaxu[(q << 5) + (t >> 4)] = m;
    }
    __syncthreads();
    if (t < 64){
      uint32_t m = cmaxu[t];
#pragma unroll
      for (int d = 1; d <= 32; d <<= 1){
        uint32_t o = (uint32_t)__shfl_xor((int)m, d);
        m = (o < m) ? o : m;
      }
      if (t == 0) Tu_sh = m;
    }
    __syncthreads();
    uint32_t Tu = Tu_sh;
#pragma unroll
    for (int q = 0; q < 2; ++q){
      int j = t + q*512;
      bool keep = (!unclip[q]) && (bitsr[q] >= Tu);
      ull bm = __ballot(keep);
      int cnt = __popcll(bm);
      int base = 0;
      if (l == 0) base = atomicAdd(&ncand_sh, cnt);
      base = __shfl(base, 0);
      if (keep){
        int pos = base + __popcll(bm & ltm);
        if (pos < 512) cand[pos] = (unsigned short)j;
        else ovf2_sh = 1;
      }
    }
    __syncthreads();
  }
  int ncand = ncand_sh;
  bool full = ovf || (ovf2_sh != 0) || (ncand > 512);

  if (!full){
    // ---- phase 5: exact keys for candidates only, wave sort + merge tree ----
    ull kkey = 0ull;
    if (t < ncand){
      int j = cand[t];
      float v = logf(cons_sh[j] / rowsum) + gumbel_from(ubits_sh[j]);
      kkey = packkey(v, (uint32_t)j);
    }
    if (wv * 64 < ncand){
      kkey = sort32_desc(kkey, l);
      kkey = mergehalves_desc(kkey, l);
    }
    if (l < 32) sbuf[(wv << 5) + l] = kkey;
    __syncthreads();
    if (wv < 4){
      ull k2 = 0ull;
      if (wv * 128 < ncand){
        k2 = (l < 32) ? sbuf[(wv << 6) + l] : sbuf[(wv << 6) + 95 - l];
        k2 = merge64_desc(k2, l);
      }
      if (l < 32) sbuf2[(wv << 5) + l] = k2;
    }
    __syncthreads();
    if (wv < 2){
      ull k2 = (l < 32) ? sbuf2[(wv << 6) + l] : sbuf2[(wv << 6) + 95 - l];
      k2 = merge64_desc(k2, l);
      if (l < 32) sbuf[(wv << 5) + l] = k2;
    }
    __syncthreads();
    if (wv == 0){
      ull k2 = (l < 32) ? sbuf[l] : sbuf[95 - l];
      k2 = merge64_desc(k2, l);
      if (l < 32) nnb[outoff + l] = (l < NG) ? (unsigned short)unpackidx(k2) : 0;
    }
  } else {
    // ---- fallback: exact keys for ALL elements, full LDS bitonic ----
    float v0 = logf(cons_sh[t] / rowsum) + gumbel_from(bitsr[0]);
    float v1 = logf(cons_sh[t + 512] / rowsum) + gumbel_from(bitsr[1]);
    ull key0 = packkey(v0, (uint32_t)t);
    ull key1 = packkey(v1, (uint32_t)(t + 512));
    __syncthreads();
    SH[t] = key0; SH[t + 512] = key1;
    __syncthreads();
    bitonic_desc(SH, NS, t, 512);
    if (t < 32) nnb[outoff + t] = (t < NG) ? (unsigned short)unpackidx(SH[t]) : 0;
  }
}

// ---------------- kernel 3: weighted Kabsch + 3x3 SVD (double) ----------------
// grid (NB*NS/64, 1, nz), block 64
__global__ __launch_bounds__(64) void ghv_kabsch(const float* __restrict__ seeds,
                                                 const unsigned short* __restrict__ nnb,
                                                 float* __restrict__ Rt,
                                                 int it0, int seq){
  int id = blockIdx.x*64 + threadIdx.x;
  int it = it0 + blockIdx.z;
  int slot = seq ? 0 : it;
  int b = id >> 10;
  const float* sdat = seeds + (size_t)slot*(NB*NS*8);
  const unsigned short* nnp = nnb + ((size_t)slot*(NB*NS) + (size_t)id)*32;

  float sxs=0, sys=0, szs=0, cxs=0, cys=0, czs=0, wsum=0;
  for (int g = 0; g < NG; ++g){
    int j = nnp[g];
    const float4* jp = (const float4*)(sdat + (size_t)((b << 10) + j)*8);
    float4 p0 = jp[0], p1 = jp[1];
    sxs += p0.x; sys += p0.y; szs += p0.z;
    cxs += p0.w; cys += p1.x; czs += p1.y;
    wsum += p1.z;
  }
  float msx = sxs/30.0f, msy = sys/30.0f, msz = szs/30.0f;
  float mcx = cxs/30.0f, mcy = cys/30.0f, mcz = czs/30.0f;

  float Hf[9] = {0,0,0,0,0,0,0,0,0};
  for (int g = 0; g < NG; ++g){
    int j = nnp[g];
    const float4* jp = (const float4*)(sdat + (size_t)((b << 10) + j)*8);
    float4 p0 = jp[0], p1 = jp[1];
    float wg = p1.z / wsum;
    float a0 = p0.x - msx, a1 = p0.y - msy, a2 = p0.z - msz;
    float b0 = p0.w - mcx, b1 = p1.x - mcy, b2 = p1.y - mcz;
    float a0w = a0*wg, a1w = a1*wg, a2w = a2*wg;
    Hf[0] += a0w*b0; Hf[1] += a0w*b1; Hf[2] += a0w*b2;
    Hf[3] += a1w*b0; Hf[4] += a1w*b1; Hf[5] += a1w*b2;
    Hf[6] += a2w*b0; Hf[7] += a2w*b1; Hf[8] += a2w*b2;
  }

  double H[9]; for (int i = 0; i < 9; ++i) H[i] = (double)Hf[i];
  double A[3][3];
  A[0][0] = H[0]*H[0] + H[3]*H[3] + H[6]*H[6];
  A[0][1] = H[0]*H[1] + H[3]*H[4] + H[6]*H[7];
  A[0][2] = H[0]*H[2] + H[3]*H[5] + H[6]*H[8];
  A[1][1] = H[1]*H[1] + H[4]*H[4] + H[7]*H[7];
  A[1][2] = H[1]*H[2] + H[4]*H[5] + H[7]*H[8];
  A[2][2] = H[2]*H[2] + H[5]*H[5] + H[8]*H[8];
  A[1][0] = A[0][1]; A[2][0] = A[0][2]; A[2][1] = A[1][2];
  double V[3][3] = {{1,0,0},{0,1,0},{0,0,1}};
  for (int sw = 0; sw < 8; ++sw){
    for (int p = 0; p < 2; ++p){
      for (int q = p+1; q < 3; ++q){
        double apq = A[p][q];
        if (fabs(apq) > 1e-300){
          double th = (A[q][q] - A[p][p]) / (2.0*apq);
          double tt = copysign(1.0, th) / (fabs(th) + sqrt(1.0 + th*th));
          double c  = 1.0 / sqrt(1.0 + tt*tt), sn = tt*c;
          int r = 3 - p - q;
          double app = A[p][p], aqq = A[q][q];
          double arp = A[r][p], arq = A[r][q];
          A[p][p] = app - tt*apq;
          A[q][q] = aqq + tt*apq;
          A[p][q] = 0.0; A[q][p] = 0.0;
          A[r][p] = c*arp - sn*arq; A[p][r] = A[r][p];
          A[r][q] = sn*arp + c*arq; A[q][r] = A[r][q];
          for (int kk = 0; kk < 3; ++kk){
            double vp = V[kk][p], vq = V[kk][q];
            V[kk][p] = c*vp - sn*vq;
            V[kk][q] = sn*vp + c*vq;
          }
        }
      }
    }
  }
  int o0 = 0, o1 = 1, o2 = 2;
  double l0 = A[0][0], l1 = A[1][1], l2 = A[2][2];
  double tmp; int ti;
  if (l0 < l1){ tmp=l0; l0=l1; l1=tmp; ti=o0; o0=o1; o1=ti; }
  if (l0 < l2){ tmp=l0; l0=l2; l2=tmp; ti=o0; o0=o2; o2=ti; }
  if (l1 < l2){ tmp=l1; l1=l2; l2=tmp; ti=o1; o1=o2; o2=ti; }
  double v0[3] = {V[0][o0], V[1][o0], V[2][o0]};
  double v1[3] = {V[0][o1], V[1][o1], V[2][o1]};
  double v2[3] = {V[0][o2], V[1][o2], V[2][o2]};

  double u0[3], u1[3], u2[3];
  for (int i = 0; i < 3; ++i) u0[i] = H[i*3+0]*v0[0] + H[i*3+1]*v0[1] + H[i*3+2]*v0[2];
  double n0 = sqrt(u0[0]*u0[0] + u0[1]*u0[1] + u0[2]*u0[2]);
  if (n0 > 1e-150){ u0[0]/=n0; u0[1]/=n0; u0[2]/=n0; }
  else { u0[0]=1; u0[1]=0; u0[2]=0; }
  for (int i = 0; i < 3; ++i) u1[i] = H[i*3+0]*v1[0] + H[i*3+1]*v1[1] + H[i*3+2]*v1[2];
  double d01 = u0[0]*u1[0] + u0[1]*u1[1] + u0[2]*u1[2];
  for (int i = 0; i < 3; ++i) u1[i] -= d01*u0[i];
  double n1 = sqrt(u1[0]*u1[0] + u1[1]*u1[1] + u1[2]*u1[2]);
  if (n1 > 1e-150){ u1[0]/=n1; u1[1]/=n1; u1[2]/=n1; }
  else {
    double ax = fabs(u0[0]), ay = fabs(u0[1]), az = fabs(u0[2]);
    double e[3] = {0,0,0};
    if (ax <= ay && ax <= az) e[0] = 1; else if (ay <= az) e[1] = 1; else e[2] = 1;
    double de = u0[0]*e[0] + u0[1]*e[1] + u0[2]*e[2];
    for (int i = 0; i < 3; ++i) u1[i] = e[i] - de*u0[i];
    double nn1 = sqrt(u1[0]*u1[0] + u1[1]*u1[1] + u1[2]*u1[2]);
    for (int i = 0; i < 3; ++i) u1[i] /= nn1;
  }
  u2[0] = u0[1]*u1[2] - u0[2]*u1[1];
  u2[1] = u0[2]*u1[0] - u0[0]*u1[2];
  u2[2] = u0[0]*u1[1] - u0[1]*u1[0];
  double detV = v0[0]*(v1[1]*v2[2] - v1[2]*v2[1])
              - v0[1]*(v1[0]*v2[2] - v1[2]*v2[0])
              + v0[2]*(v1[0]*v2[1] - v1[1]*v2[0]);
  float Rf[9];
  for (int i = 0; i < 3; ++i)
    for (int j = 0; j < 3; ++j)
      Rf[i*3+j] = (float)(v0[i]*u0[j] + v1[i]*u1[j] + detV*(v2[i]*u2[j]));
  float tx = -(Rf[0]*msx + Rf[1]*msy + Rf[2]*msz) + mcx;
  float ty = -(Rf[3]*msx + Rf[4]*msy + Rf[5]*msz) + mcy;
  float tz = -(Rf[6]*msx + Rf[7]*msy + Rf[8]*msz) + mcz;
  float* o = Rt + ((size_t)slot*(NB*NS) + (size_t)id)*12;
  for (int i = 0; i < 9; ++i) o[i] = Rf[i];
  o[9] = tx; o[10] = ty; o[11] = tz;
}

// ---------------- kernel 4: fitness, 16 seeds per block, LDS point slab ----------------
// grid (NS/16, NB, nz), block 256
__global__ __launch_bounds__(256) void ghv_fitness(const float* __restrict__ src,
                                                   const float* __restrict__ tgt,
                                                   const float* __restrict__ Rt,
                                                   int* __restrict__ fit){
  __shared__ float Pf[12288];   // [src x|y|z | tgt x|y|z] each 2048
  int b = blockIdx.y, t = threadIdx.x;
  int slot = blockIdx.z;
  int s0 = blockIdx.x * 16;
  const float4* g4s = (const float4*)(src + (size_t)b*3*NPTS);
  const float4* g4t = (const float4*)(tgt + (size_t)b*3*NPTS);
  float4* l4 = (float4*)Pf;
  for (int i = t; i < 1536; i += 256){
    l4[i] = g4s[i];
    l4[1536 + i] = g4t[i];
  }
  __syncthreads();
  int wv = t >> 6, l = t & 63;
  for (int k = 0; k < 4; ++k){
    int s = s0 + wv*4 + k;
    size_t id = (size_t)slot*(NB*NS) + (size_t)((b << 10) + s);
    const float* rt = Rt + id*12;
    float R0 = rt[0], R1 = rt[1], R2 = rt[2];
    float R3 = rt[3], R4 = rt[4], R5 = rt[5];
    float R6 = rt[6], R7 = rt[7], R8 = rt[8];
    float t0 = rt[9], t1 = rt[10], t2 = rt[11];
    int cnt = 0;
    for (int n = l; n < NPTS; n += 64){
      float x = Pf[n], y = Pf[2048 + n], z = Pf[4096 + n];
      float px = R0*x + R1*y + R2*z + t0;
      float py = R3*x + R4*y + R5*z + t1;
      float pz = R6*x + R7*y + R8*z + t2;
      float dx = px - Pf[6144 + n], dy = py - Pf[8192 + n], dz = pz - Pf[10240 + n];
      float l2 = sqrtf(dx*dx + dy*dy + dz*dz);
      cnt += (l2 < 0.1f) ? 1 : 0;
    }
    for (int off = 32; off >= 1; off >>= 1) cnt += __shfl_down(cnt, off);
    if (l == 0) fit[id] = cnt;
  }
}

// ---------------- kernel 5a: batched final select over all iterations ----------------
__global__ __launch_bounds__(512) void ghv_select_b(const float* __restrict__ Rt,
                                                    const int* __restrict__ fit,
                                                    float* __restrict__ out){
  __shared__ int mc[NITER*NB], mi[NITER*NB];
  __shared__ int best_sh;
  int t = threadIdx.x;
  int w = t >> 6, l = t & 63;
  for (int task = w; task < NITER*NB; task += 8){
    int it = task >> 3, b = task & 7;
    int bc = -1, bi = 0;
    const int* fp = fit + (size_t)it*(NB*NS) + (b << 10);
    for (int s = l; s < NS; s += 64){
      int c = fp[s];
      if (c > bc){ bc = c; bi = s; }
    }
    for (int off = 32; off >= 1; off >>= 1){
      int oc = __shfl_down(bc, off);
      int oi = __shfl_down(bi, off);
      if (oc > bc || (oc == bc && oi < bi)){ bc = oc; bi = oi; }
    }
    if (l == 0){ mc[task] = bc; mi[task] = bi; }
  }
  __syncthreads();
  if (t == 0){
    float dist = 1e8f;
    int best = 0;
    for (int it = 0; it < NITER; ++it){
      int sum = 0;
      for (int b = 0; b < NB; ++b) sum += mc[(it << 3) + b];
      float vv = (float)sum / 16384.0f;
      if (vv < dist){ dist = vv; best = it; }
    }
    best_sh = best;
  }
  __syncthreads();
  int bit = best_sh;
  for (int i = t; i < 96; i += 512){
    float v;
    if (i < 72){
      int bb = i / 9, k = i % 9;
      v = Rt[((size_t)bit*(NB*NS) + (size_t)((bb << 10) + mi[(bit << 3) + bb]))*12 + k];
    } else {
      int ii = i - 72; int bb = ii / 3, k = ii % 3;
      v = Rt[((size_t)bit*(NB*NS) + (size_t)((bb << 10) + mi[(bit << 3) + bb]))*12 + 9 + k];
    }
    out[i] = v;
  }
}

// ---------------- kernel 5b: sequential-path select (fallback) ----------------
__global__ __launch_bounds__(512) void ghv_select_s(const float* __restrict__ Rt,
                                                    const int* __restrict__ fit,
                                                    float* __restrict__ dist_ws,
                                                    float* __restrict__ out,
                                                    int first){
  __shared__ int mc[8], mi[8];
  __shared__ int flag;
  int t = threadIdx.x;
  int b = t >> 6, lane = t & 63;
  int bc = -1, bi = 0;
  for (int s = lane; s < NS; s += 64){
    int c = fit[(b << 10) + s];
    if (c > bc){ bc = c; bi = s; }
  }
  for (int off = 32; off >= 1; off >>= 1){
    int oc = __shfl_down(bc, off);
    int oi = __shfl_down(bi, off);
    if (oc > bc || (oc == bc && oi < bi)){ bc = oc; bi = oi; }
  }
  if (lane == 0){ mc[b] = bc; mi[b] = bi; }
  __syncthreads();
  if (t == 0){
    int sum = 0; for (int i = 0; i < 8; ++i) sum += mc[i];
    float vv = (float)sum / 16384.0f;
    float dist = first ? 1e8f : dist_ws[0];
    int better = (vv < dist) ? 1 : 0;
    if (better) dist_ws[0] = vv;
    flag = better;
  }
  __syncthreads();
  if (flag){
    for (int i = t; i < 96; i += 512){
      float v;
      if (i < 72){
        int bb = i / 9, k = i % 9;
        v = Rt[(size_t)((bb << 10) + mi[bb])*12 + k];
      } else {
        int ii = i - 72; int bb = ii / 3, k = ii % 3;
        v = Rt[(size_t)((bb << 10) + mi[bb])*12 + 9 + k];
      }
      out[i] = v;
    }
  }
}

// ---------------- host ----------------
extern "C" void kernel_launch(void* const* d_in, const int* in_sizes, int n_in,
                              void* d_out, int out_size, void* d_ws, size_t ws_size,
                              hipStream_t stream){
  const float* src = (const float*)d_in[0];
  const float* tgt = (const float*)d_in[1];
  const float* win = (const float*)d_in[2];
  float* out = (float*)d_out;
  char* ws = (char*)d_ws;

  const size_t SEEDS_SZ = (size_t)NB*NS*8*4;     // 262144
  const size_t RT_SZ    = (size_t)NB*NS*12*4;    // 393216
  const size_t NN_SZ    = (size_t)NB*NS*32*2;    // 524288
  const size_t FIT_SZ   = (size_t)NB*NS*4;       // 32768
  const size_t W_SZ     = (size_t)NB*NPTS*4;     // 65536

  size_t off_w    = 0;
  size_t off_logw = off_w + W_SZ;
  size_t off_seed = off_logw + W_SZ;
  size_t off_Rt   = off_seed + NITER*SEEDS_SZ;
  size_t off_nn   = off_Rt + NITER*RT_SZ;
  size_t off_fit  = off_nn + NITER*NN_SZ;
  size_t need_b   = off_fit + NITER*FIT_SZ;

  if (ws_size >= need_b){
    float* w     = (float*)(ws + off_w);
    float* logw  = (float*)(ws + off_logw);
    float* seeds = (float*)(ws + off_seed);
    float* Rt    = (float*)(ws + off_Rt);
    unsigned short* nnb = (unsigned short*)(ws + off_nn);
    int*   fit   = (int*)(ws + off_fit);

    ghv_softmax<<<NB, 256, 0, stream>>>(win, w, logw);
    ghv_seed   <<<dim3(NB, 1, NITER), 1024, 0, stream>>>(src, tgt, w, logw, seeds, 0, 0);
    ghv_nn     <<<dim3(NS, NB, NITER), 512, 0, stream>>>(seeds, nnb, 0, 0);
    ghv_kabsch <<<dim3(NB*NS/64, 1, NITER), 64, 0, stream>>>(seeds, nnb, Rt, 0, 0);
    ghv_fitness<<<dim3(NS/16, NB, NITER), 256, 0, stream>>>(src, tgt, Rt, fit);
    ghv_select_b<<<1, 512, 0, stream>>>(Rt, fit, out);
  } else {
    size_t o_w = 0, o_lw = W_SZ, o_sd = 2*W_SZ, o_rt = o_sd + SEEDS_SZ,
           o_nn2 = o_rt + RT_SZ, o_ft = o_nn2 + NN_SZ, o_ds = o_ft + FIT_SZ;
    float* w     = (float*)(ws + o_w);
    float* logw  = (float*)(ws + o_lw);
    float* seeds = (float*)(ws + o_sd);
    float* Rt    = (float*)(ws + o_rt);
    unsigned short* nnb = (unsigned short*)(ws + o_nn2);
    int*   fit   = (int*)(ws + o_ft);
    float* dist  = (float*)(ws + o_ds);

    ghv_softmax<<<NB, 256, 0, stream>>>(win, w, logw);
    for (int it = 0; it < NITER; ++it){
      ghv_seed   <<<dim3(NB, 1, 1), 1024, 0, stream>>>(src, tgt, w, logw, seeds, it, 1);
      ghv_nn     <<<dim3(NS, NB, 1), 512, 0, stream>>>(seeds, nnb, it, 1);
      ghv_kabsch <<<dim3(NB*NS/64, 1, 1), 64, 0, stream>>>(seeds, nnb, Rt, it, 1);
      ghv_fitness<<<dim3(NS/16, NB, 1), 256, 0, stream>>>(src, tgt, Rt, fit);
      ghv_select_s<<<1, 512, 0, stream>>>(Rt, fit, dist, out, (it == 0) ? 1 : 0);
    }
  }
}

// Round 6
// 951.458 us; speedup vs baseline: 1.1468x; 1.1468x over previous
//
#include <hip/hip_runtime.h>
#include <stdint.h>
#include <math.h>

// Match XLA-CPU's unfused mul/add on threshold-critical math.
#pragma clang fp contract(off)

#define NB    8
#define NPTS  2048
#define NS    1024
#define NG    30
#define NITER 10

typedef unsigned long long ull;

// ---------------- threefry2x32 (Random123 / JAX, 20 rounds) ----------------
__host__ __device__ __forceinline__ uint32_t rotl32(uint32_t x, int r){
  return (x << r) | (x >> (32 - r));
}
__host__ __device__ __forceinline__ void tf2x32(uint32_t k0, uint32_t k1,
                                                uint32_t x0, uint32_t x1,
                                                uint32_t& o0, uint32_t& o1){
  uint32_t k2 = k0 ^ k1 ^ 0x1BD11BDAu;
  x0 += k0; x1 += k1;
#define TFR(r) { x0 += x1; x1 = rotl32(x1, (r)); x1 ^= x0; }
  TFR(13) TFR(15) TFR(26) TFR(6)
  x0 += k1; x1 += k2 + 1u;
  TFR(17) TFR(29) TFR(16) TFR(24)
  x0 += k2; x1 += k0 + 2u;
  TFR(13) TFR(15) TFR(26) TFR(6)
  x0 += k0; x1 += k1 + 3u;
  TFR(17) TFR(29) TFR(16) TFR(24)
  x0 += k1; x1 += k2 + 4u;
  TFR(13) TFR(15) TFR(26) TFR(6)
  x0 += k2; x1 += k0 + 5u;
#undef TFR
  o0 = x0; o1 = x1;
}

// partitionable threefry: bits[e] = o0^o1 of tf(key,(0,e))
__device__ __forceinline__ uint32_t rand_bits(uint32_t k0, uint32_t k1, uint32_t e){
  uint32_t o0, o1; tf2x32(k0, k1, 0u, e, o0, o1);
  return o0 ^ o1;
}

// split(fold_in(key(42), it)): k_i = tf(folded, (0, i)), i in {0,1}
__device__ __forceinline__ void derive_key(int it, uint32_t which,
                                           uint32_t& a, uint32_t& b){
  uint32_t fa, fb;
  tf2x32(0u, 42u, 0u, (uint32_t)it, fa, fb);
  tf2x32(fa, fb, 0u, which, a, b);
}

// jax.random.uniform(minval=1e-9, maxval=1.0) -> gumbel  (monotone in bits>>9)
__device__ __forceinline__ float gumbel_from(uint32_t bits){
  float f = __uint_as_float((bits >> 9) | 0x3f800000u) - 1.0f;  // [0,1)
  float u = fmaxf(1e-9f, f + 1e-9f);
  return -logf(-logf(u));
}

// ---------------- sort keys: (value desc, index asc) ----------------
__device__ __forceinline__ ull packkey(float v, uint32_t idx){
  uint32_t u = __float_as_uint(v);
  u = (u & 0x80000000u) ? ~u : (u | 0x80000000u);
  return ((ull)u << 32) | (ull)(0xFFFFFFFFu - idx);
}
__device__ __forceinline__ uint32_t unpackidx(ull k){
  return 0xFFFFFFFFu - (uint32_t)(k & 0xFFFFFFFFull);
}

__device__ __forceinline__ void bitonic_desc(ull* a, int M, int t, int T){
  for (int k = 2; k <= M; k <<= 1){
    for (int j = k >> 1; j > 0; j >>= 1){
      for (int i = t; i < M; i += T){
        int ixj = i ^ j;
        if (ixj > i){
          ull ai = a[i], aj = a[ixj];
          bool desc = ((i & k) == 0);
          if (desc ? (ai < aj) : (ai > aj)){ a[i] = aj; a[ixj] = ai; }
        }
      }
      __syncthreads();
    }
  }
}

// -------- wave-level (64-lane) register bitonic helpers, u64 keys --------
__device__ __forceinline__ ull shfl_xor_u64(ull x, int mask){
  return (ull)__shfl_xor((long long)x, mask, 64);
}

__device__ __forceinline__ ull sort32_desc(ull key, int l){
  int i = l & 31;
#pragma unroll
  for (int k = 2; k <= 16; k <<= 1){
#pragma unroll
    for (int j = k >> 1; j > 0; j >>= 1){
      ull other = shfl_xor_u64(key, j);
      bool up = ((l & j) == 0);
      bool take_max = (((i & k) == 0) == up);
      bool omax = other > key;
      key = (take_max == omax) ? other : key;
    }
  }
#pragma unroll
  for (int j = 16; j > 0; j >>= 1){
    ull other = shfl_xor_u64(key, j);
    bool up = ((l & j) == 0);
    bool omax = other > key;
    key = (up == omax) ? other : key;
  }
  return key;
}

__device__ __forceinline__ ull merge64_desc(ull key, int l){
#pragma unroll
  for (int j = 32; j > 0; j >>= 1){
    ull other = shfl_xor_u64(key, j);
    bool up = ((l & j) == 0);
    bool omax = other > key;
    key = (up == omax) ? other : key;
  }
  return key;
}

__device__ __forceinline__ ull mergehalves_desc(ull key, int l){
  ull rev = shfl_xor_u64(key, 31);
  if (l >= 32) key = rev;
  return merge64_desc(key, l);
}

// ---------------- kernel 0: nan/inf cleanup + softmax + log ----------------
__global__ __launch_bounds__(256) void ghv_softmax(const float* __restrict__ win,
                                                   float* __restrict__ w,
                                                   float* __restrict__ logw){
  int b = blockIdx.x, t = threadIdx.x;
  __shared__ float sh[NPTS];
  __shared__ float red[4];
  __shared__ float bcast;
  for (int n = t; n < NPTS; n += 256){
    float x = win[b*NPTS + n];
    if (isnan(x)) x = 1e-7f;
    if (isinf(x)) x = 1.0f;
    sh[n] = x;
  }
  __syncthreads();
  float m = -INFINITY;
  for (int n = t; n < NPTS; n += 256) m = fmaxf(m, sh[n]);
  for (int off = 32; off >= 1; off >>= 1) m = fmaxf(m, __shfl_down(m, off));
  if ((t & 63) == 0) red[t >> 6] = m;
  __syncthreads();
  if (t == 0) bcast = fmaxf(fmaxf(red[0], red[1]), fmaxf(red[2], red[3]));
  __syncthreads();
  float mx = bcast;
  float ss = 0.0f;
  for (int n = t; n < NPTS; n += 256){ float e = expf(sh[n] - mx); sh[n] = e; ss += e; }
  for (int off = 32; off >= 1; off >>= 1) ss += __shfl_down(ss, off);
  if ((t & 63) == 0) red[t >> 6] = ss;
  __syncthreads();
  if (t == 0) bcast = red[0] + red[1] + red[2] + red[3];
  __syncthreads();
  float tot = bcast;
  for (int n = t; n < NPTS; n += 256){
    float wv = sh[n] / tot;
    w[b*NPTS + n] = wv;
    logw[b*NPTS + n] = logf(wv);
  }
}

// ---------------- kernel 1: seed gumbel top-1024 + gather ----------------
__global__ __launch_bounds__(1024) void ghv_seed(const float* __restrict__ src,
                                                 const float* __restrict__ tgt,
                                                 const float* __restrict__ w,
                                                 const float* __restrict__ logw,
                                                 float* __restrict__ seeds,
                                                 int it0, int seq){
  __shared__ ull keys[NPTS];
  __shared__ uint32_t kk[2];
  int b = blockIdx.x, t = threadIdx.x;
  int it = it0 + blockIdx.z;
  int slot = seq ? 0 : it;
  if (t == 0){ derive_key(it, 0u, kk[0], kk[1]); }
  __syncthreads();
  uint32_t k0 = kk[0], k1 = kk[1];
  for (int n = t; n < NPTS; n += 1024){
    uint32_t bits = rand_bits(k0, k1, (uint32_t)(b*NPTS + n));
    float v = logw[b*NPTS + n] + gumbel_from(bits);
    keys[n] = packkey(v, (uint32_t)n);
  }
  __syncthreads();
  bitonic_desc(keys, NPTS, t, 1024);
  int s = t;
  uint32_t idx = unpackidx(keys[s]);
  const float* sb = src + b*3*NPTS;
  const float* tb = tgt + b*3*NPTS;
  float* sp = seeds + (size_t)slot*(NB*NS*8) + (size_t)((b << 10) + s) * 8;
  sp[0] = sb[idx]; sp[1] = sb[NPTS + idx]; sp[2] = sb[2*NPTS + idx];
  sp[3] = tb[idx]; sp[4] = tb[NPTS + idx]; sp[5] = tb[2*NPTS + idx];
  sp[6] = w[b*NPTS + idx]; sp[7] = 0.0f;
}

// ---------------- kernel 2: consensus + gumbel top-30 per (b,s) row ----------------
// R4 skeleton + deferred v-pass: the div+3*logf key math runs only for
// candidates = unclipped ∪ (clipped with f=bits>>9 ≥ fT), fT = min over 32
// chunk-maxes of clipped f (exact: ≥32 strictly-f-greater clipped dominate
// any excluded element). No atomics; ballot+prefix compaction.
// grid (NS, NB, nz), block 512
__global__ __launch_bounds__(512) void ghv_nn(const float* __restrict__ seeds,
                                              unsigned short* __restrict__ nnb,
                                              int it0, int seq){
  __shared__ ull UN[1024];            // [cons f32 x1024 | kbuf ull x512]; fallback: keys x1024
  __shared__ ull sbuf[256];
  __shared__ ull sbuf2[128];
  __shared__ unsigned short candi[512];
  __shared__ float red[8];
  __shared__ float srow[8];
  __shared__ float rowsum_sh;
  __shared__ uint32_t cmax32[32];
  __shared__ uint32_t fT_sh;
  __shared__ int wcnt[8];
  __shared__ uint32_t kk[2];

  float* cons_sh = (float*)UN;        // bytes [0, 4096)
  ull* kbuf = UN + 512;               // bytes [4096, 8192)

  int s = blockIdx.x, b = blockIdx.y, t = threadIdx.x;
  int it = it0 + blockIdx.z;
  int slot = seq ? 0 : it;
  const float* sdat = seeds + (size_t)slot*(NB*NS*8);
  size_t outoff = ((size_t)slot*(NB*NS) + (size_t)((b << 10) + s))*32;
  int wv = t >> 6, l = t & 63;

  if (t < 8) srow[t] = sdat[(size_t)((b << 10) + s)*8 + t];
  if (t == 0){ derive_key(it, 1u, kk[0], kk[1]); }
  __syncthreads();
  uint32_t k0 = kk[0], k1 = kk[1];
  ull ltm = (l == 0) ? 0ull : ((1ull << l) - 1ull);
  uint32_t eb = (uint32_t)((b << 20) + (s << 10));

  // ---- phase 1: distances, cons (predicated expf, identical to R4), bits ----
  float consr[2]; bool clipped[2]; uint32_t bitsr[2];
  float part = 0.0f;
#pragma unroll
  for (int q = 0; q < 2; ++q){
    int j = t + q*512;
    const float4* jp = (const float4*)(sdat + (size_t)((b << 10) + j)*8);
    float4 p0 = jp[0], p1 = jp[1];
    float dxs = srow[0]-p0.x, dys = srow[1]-p0.y, dzs = srow[2]-p0.z;
    float ds  = sqrtf(dxs*dxs + dys*dys + dzs*dzs);
    float dxc = srow[3]-p0.w, dyc = srow[4]-p1.x, dzc = srow[5]-p1.y;
    float dc  = sqrtf(dxc*dxc + dyc*dyc + dzc*dzc);
    float diff = ds - dc;
    float arg = (-(diff*diff)) / 0.01f;
    // conservative: arg < -2.3026f => expf(arg) < 0.1 certainly => cons == 0.1f
    clipped[q] = (arg < -2.3026f);
    float cons = fmaxf(expf(arg), 0.1f);
    consr[q] = cons;
    cons_sh[j] = cons;
    bitsr[q] = rand_bits(k0, k1, eb + (uint32_t)j);
    part += cons;
  }

  // ---- rowsum (identical tree to R4) ----
  for (int off = 32; off >= 1; off >>= 1) part += __shfl_down(part, off);
  if ((t & 63) == 0) red[t >> 6] = part;
  __syncthreads();
  if (t == 0){ float tot = 0.0f; for (int i = 0; i < 8; ++i) tot += red[i]; rowsum_sh = tot; }
  __syncthreads();
  float rowsum = rowsum_sh;

  // ---- f-threshold over clipped (32 chunks of 32 consecutive elements) ----
#pragma unroll
  for (int q = 0; q < 2; ++q){
    uint32_t m = clipped[q] ? (bitsr[q] >> 9) : 0u;
#pragma unroll
    for (int d = 1; d <= 16; d <<= 1){
      uint32_t o = (uint32_t)__shfl_xor((int)m, d);
      m = (o > m) ? o : m;
    }
    if ((l & 31) == 0) cmax32[(q << 4) + (t >> 5)] = m;
  }
  __syncthreads();
  if (t < 32){
    uint32_t m = cmax32[t];
#pragma unroll
    for (int d = 1; d <= 16; d <<= 1){
      uint32_t o = (uint32_t)__shfl_xor((int)m, d);
      m = (o < m) ? o : m;
    }
    if (t == 0) fT_sh = m;
  }
  __syncthreads();
  uint32_t fT = fT_sh;

  // ---- candidacy + atomic-free compaction ----
  bool cand0 = (!clipped[0]) || ((bitsr[0] >> 9) >= fT);
  bool cand1 = (!clipped[1]) || ((bitsr[1] >> 9) >= fT);
  ull m0 = __ballot(cand0), m1 = __ballot(cand1);
  int c0 = __popcll(m0), c1 = __popcll(m1);
  if (l == 0) wcnt[wv] = c0 + c1;
  __syncthreads();
  int base = 0, ncand = 0;
#pragma unroll
  for (int i = 0; i < 8; ++i){
    int c = wcnt[i];
    if (i < wv) base += c;
    ncand += c;
  }
  if (cand0){
    int pos = base + __popcll(m0 & ltm);
    if (pos < 512) candi[pos] = (unsigned short)t;
  }
  if (cand1){
    int pos = base + c0 + __popcll(m1 & ltm);
    if (pos < 512) candi[pos] = (unsigned short)(t + 512);
  }
  __syncthreads();

  if (ncand <= 512){
    // ---- dense v-pass for candidates only ----
    ull kkey = 0ull;
    if (t < ncand){
      int j = candi[t];
      uint32_t bits = rand_bits(k0, k1, eb + (uint32_t)j);
      float v = logf(cons_sh[j] / rowsum) + gumbel_from(bits);
      kkey = packkey(v, (uint32_t)j);
    }
    if (wv * 64 < ncand){
      kkey = sort32_desc(kkey, l);
      kkey = mergehalves_desc(kkey, l);
    }
    if (l < 32) sbuf[(wv << 5) + l] = kkey;
    __syncthreads();
    if (wv < 4){
      ull k2 = 0ull;
      if (wv * 128 < ncand){
        k2 = (l < 32) ? sbuf[(wv << 6) + l] : sbuf[(wv << 6) + 95 - l];
        k2 = merge64_desc(k2, l);
      }
      if (l < 32) sbuf2[(wv << 5) + l] = k2;
    }
    __syncthreads();
    if (wv < 2){
      ull k2 = (l < 32) ? sbuf2[(wv << 6) + l] : sbuf2[(wv << 6) + 95 - l];
      k2 = merge64_desc(k2, l);
      if (l < 32) sbuf[(wv << 5) + l] = k2;
    }
    __syncthreads();
    if (wv == 0){
      ull k2 = (l < 32) ? sbuf[l] : sbuf[95 - l];
      k2 = merge64_desc(k2, l);
      if (l < 32) nnb[outoff + l] = (l < NG) ? (unsigned short)unpackidx(k2) : 0;
    }
  } else {
    // ---- fallback: exact keys for ALL elements (from regs), full bitonic ----
    float v0 = logf(consr[0] / rowsum) + gumbel_from(bitsr[0]);
    float v1 = logf(consr[1] / rowsum) + gumbel_from(bitsr[1]);
    ull key0 = packkey(v0, (uint32_t)t);
    ull key1 = packkey(v1, (uint32_t)(t + 512));
    __syncthreads();
    UN[t] = key0; UN[t + 512] = key1;
    __syncthreads();
    bitonic_desc(UN, NS, t, 512);
    if (t < 32) nnb[outoff + t] = (t < NG) ? (unsigned short)unpackidx(UN[t]) : 0;
  }
}

// ---------------- kernel 3: weighted Kabsch + 3x3 SVD (double) ----------------
// grid (NB*NS/64, 1, nz), block 64
__global__ __launch_bounds__(64) void ghv_kabsch(const float* __restrict__ seeds,
                                                 const unsigned short* __restrict__ nnb,
                                                 float* __restrict__ Rt,
                                                 int it0, int seq){
  int id = blockIdx.x*64 + threadIdx.x;
  int it = it0 + blockIdx.z;
  int slot = seq ? 0 : it;
  int b = id >> 10;
  const float* sdat = seeds + (size_t)slot*(NB*NS*8);
  const unsigned short* nnp = nnb + ((size_t)slot*(NB*NS) + (size_t)id)*32;

  float sxs=0, sys=0, szs=0, cxs=0, cys=0, czs=0, wsum=0;
  for (int g = 0; g < NG; ++g){
    int j = nnp[g];
    const float4* jp = (const float4*)(sdat + (size_t)((b << 10) + j)*8);
    float4 p0 = jp[0], p1 = jp[1];
    sxs += p0.x; sys += p0.y; szs += p0.z;
    cxs += p0.w; cys += p1.x; czs += p1.y;
    wsum += p1.z;
  }
  float msx = sxs/30.0f, msy = sys/30.0f, msz = szs/30.0f;
  float mcx = cxs/30.0f, mcy = cys/30.0f, mcz = czs/30.0f;

  float Hf[9] = {0,0,0,0,0,0,0,0,0};
  for (int g = 0; g < NG; ++g){
    int j = nnp[g];
    const float4* jp = (const float4*)(sdat + (size_t)((b << 10) + j)*8);
    float4 p0 = jp[0], p1 = jp[1];
    float wg = p1.z / wsum;
    float a0 = p0.x - msx, a1 = p0.y - msy, a2 = p0.z - msz;
    float b0 = p0.w - mcx, b1 = p1.x - mcy, b2 = p1.y - mcz;
    float a0w = a0*wg, a1w = a1*wg, a2w = a2*wg;
    Hf[0] += a0w*b0; Hf[1] += a0w*b1; Hf[2] += a0w*b2;
    Hf[3] += a1w*b0; Hf[4] += a1w*b1; Hf[5] += a1w*b2;
    Hf[6] += a2w*b0; Hf[7] += a2w*b1; Hf[8] += a2w*b2;
  }

  double H[9]; for (int i = 0; i < 9; ++i) H[i] = (double)Hf[i];
  double A[3][3];
  A[0][0] = H[0]*H[0] + H[3]*H[3] + H[6]*H[6];
  A[0][1] = H[0]*H[1] + H[3]*H[4] + H[6]*H[7];
  A[0][2] = H[0]*H[2] + H[3]*H[5] + H[6]*H[8];
  A[1][1] = H[1]*H[1] + H[4]*H[4] + H[7]*H[7];
  A[1][2] = H[1]*H[2] + H[4]*H[5] + H[7]*H[8];
  A[2][2] = H[2]*H[2] + H[5]*H[5] + H[8]*H[8];
  A[1][0] = A[0][1]; A[2][0] = A[0][2]; A[2][1] = A[1][2];
  double V[3][3] = {{1,0,0},{0,1,0},{0,0,1}};
  for (int sw = 0; sw < 8; ++sw){
    for (int p = 0; p < 2; ++p){
      for (int q = p+1; q < 3; ++q){
        double apq = A[p][q];
        if (fabs(apq) > 1e-300){
          double th = (A[q][q] - A[p][p]) / (2.0*apq);
          double tt = copysign(1.0, th) / (fabs(th) + sqrt(1.0 + th*th));
          double c  = 1.0 / sqrt(1.0 + tt*tt), sn = tt*c;
          int r = 3 - p - q;
          double app = A[p][p], aqq = A[q][q];
          double arp = A[r][p], arq = A[r][q];
          A[p][p] = app - tt*apq;
          A[q][q] = aqq + tt*apq;
          A[p][q] = 0.0; A[q][p] = 0.0;
          A[r][p] = c*arp - sn*arq; A[p][r] = A[r][p];
          A[r][q] = sn*arp + c*arq; A[q][r] = A[r][q];
          for (int kk = 0; kk < 3; ++kk){
            double vp = V[kk][p], vq = V[kk][q];
            V[kk][p] = c*vp - sn*vq;
            V[kk][q] = sn*vp + c*vq;
          }
        }
      }
    }
  }
  int o0 = 0, o1 = 1, o2 = 2;
  double l0 = A[0][0], l1 = A[1][1], l2 = A[2][2];
  double tmp; int ti;
  if (l0 < l1){ tmp=l0; l0=l1; l1=tmp; ti=o0; o0=o1; o1=ti; }
  if (l0 < l2){ tmp=l0; l0=l2; l2=tmp; ti=o0; o0=o2; o2=ti; }
  if (l1 < l2){ tmp=l1; l1=l2; l2=tmp; ti=o1; o1=o2; o2=ti; }
  double v0[3] = {V[0][o0], V[1][o0], V[2][o0]};
  double v1[3] = {V[0][o1], V[1][o1], V[2][o1]};
  double v2[3] = {V[0][o2], V[1][o2], V[2][o2]};

  double u0[3], u1[3], u2[3];
  for (int i = 0; i < 3; ++i) u0[i] = H[i*3+0]*v0[0] + H[i*3+1]*v0[1] + H[i*3+2]*v0[2];
  double n0 = sqrt(u0[0]*u0[0] + u0[1]*u0[1] + u0[2]*u0[2]);
  if (n0 > 1e-150){ u0[0]/=n0; u0[1]/=n0; u0[2]/=n0; }
  else { u0[0]=1; u0[1]=0; u0[2]=0; }
  for (int i = 0; i < 3; ++i) u1[i] = H[i*3+0]*v1[0] + H[i*3+1]*v1[1] + H[i*3+2]*v1[2];
  double d01 = u0[0]*u1[0] + u0[1]*u1[1] + u0[2]*u1[2];
  for (int i = 0; i < 3; ++i) u1[i] -= d01*u0[i];
  double n1 = sqrt(u1[0]*u1[0] + u1[1]*u1[1] + u1[2]*u1[2]);
  if (n1 > 1e-150){ u1[0]/=n1; u1[1]/=n1; u1[2]/=n1; }
  else {
    double ax = fabs(u0[0]), ay = fabs(u0[1]), az = fabs(u0[2]);
    double e[3] = {0,0,0};
    if (ax <= ay && ax <= az) e[0] = 1; else if (ay <= az) e[1] = 1; else e[2] = 1;
    double de = u0[0]*e[0] + u0[1]*e[1] + u0[2]*e[2];
    for (int i = 0; i < 3; ++i) u1[i] = e[i] - de*u0[i];
    double nn1 = sqrt(u1[0]*u1[0] + u1[1]*u1[1] + u1[2]*u1[2]);
    for (int i = 0; i < 3; ++i) u1[i] /= nn1;
  }
  u2[0] = u0[1]*u1[2] - u0[2]*u1[1];
  u2[1] = u0[2]*u1[0] - u0[0]*u1[2];
  u2[2] = u0[0]*u1[1] - u0[1]*u1[0];
  double detV = v0[0]*(v1[1]*v2[2] - v1[2]*v2[1])
              - v0[1]*(v1[0]*v2[2] - v1[2]*v2[0])
              + v0[2]*(v1[0]*v2[1] - v1[1]*v2[0]);
  float Rf[9];
  for (int i = 0; i < 3; ++i)
    for (int j = 0; j < 3; ++j)
      Rf[i*3+j] = (float)(v0[i]*u0[j] + v1[i]*u1[j] + detV*(v2[i]*u2[j]));
  float tx = -(Rf[0]*msx + Rf[1]*msy + Rf[2]*msz) + mcx;
  float ty = -(Rf[3]*msx + Rf[4]*msy + Rf[5]*msz) + mcy;
  float tz = -(Rf[6]*msx + Rf[7]*msy + Rf[8]*msz) + mcz;
  float* o = Rt + ((size_t)slot*(NB*NS) + (size_t)id)*12;
  for (int i = 0; i < 9; ++i) o[i] = Rf[i];
  o[9] = tx; o[10] = ty; o[11] = tz;
}

// ---------------- kernel 4: fitness, 16 seeds per block, LDS point slab ----------------
// grid (NS/16, NB, nz), block 256
__global__ __launch_bounds__(256) void ghv_fitness(const float* __restrict__ src,
                                                   const float* __restrict__ tgt,
                                                   const float* __restrict__ Rt,
                                                   int* __restrict__ fit){
  __shared__ float Pf[12288];   // [src x|y|z | tgt x|y|z] each 2048
  int b = blockIdx.y, t = threadIdx.x;
  int slot = blockIdx.z;
  int s0 = blockIdx.x * 16;
  const float4* g4s = (const float4*)(src + (size_t)b*3*NPTS);
  const float4* g4t = (const float4*)(tgt + (size_t)b*3*NPTS);
  float4* l4 = (float4*)Pf;
  for (int i = t; i < 1536; i += 256){
    l4[i] = g4s[i];
    l4[1536 + i] = g4t[i];
  }
  __syncthreads();
  int wv = t >> 6, l = t & 63;
  for (int k = 0; k < 4; ++k){
    int s = s0 + wv*4 + k;
    size_t id = (size_t)slot*(NB*NS) + (size_t)((b << 10) + s);
    const float* rt = Rt + id*12;
    float R0 = rt[0], R1 = rt[1], R2 = rt[2];
    float R3 = rt[3], R4 = rt[4], R5 = rt[5];
    float R6 = rt[6], R7 = rt[7], R8 = rt[8];
    float t0 = rt[9], t1 = rt[10], t2 = rt[11];
    int cnt = 0;
    for (int n = l; n < NPTS; n += 64){
      float x = Pf[n], y = Pf[2048 + n], z = Pf[4096 + n];
      float px = R0*x + R1*y + R2*z + t0;
      float py = R3*x + R4*y + R5*z + t1;
      float pz = R6*x + R7*y + R8*z + t2;
      float dx = px - Pf[6144 + n], dy = py - Pf[8192 + n], dz = pz - Pf[10240 + n];
      float l2 = sqrtf(dx*dx + dy*dy + dz*dz);
      cnt += (l2 < 0.1f) ? 1 : 0;
    }
    for (int off = 32; off >= 1; off >>= 1) cnt += __shfl_down(cnt, off);
    if (l == 0) fit[id] = cnt;
  }
}

// ---------------- kernel 5a: batched final select over all iterations ----------------
__global__ __launch_bounds__(512) void ghv_select_b(const float* __restrict__ Rt,
                                                    const int* __restrict__ fit,
                                                    float* __restrict__ out){
  __shared__ int mc[NITER*NB], mi[NITER*NB];
  __shared__ int best_sh;
  int t = threadIdx.x;
  int w = t >> 6, l = t & 63;
  for (int task = w; task < NITER*NB; task += 8){
    int it = task >> 3, b = task & 7;
    int bc = -1, bi = 0;
    const int* fp = fit + (size_t)it*(NB*NS) + (b << 10);
    for (int s = l; s < NS; s += 64){
      int c = fp[s];
      if (c > bc){ bc = c; bi = s; }
    }
    for (int off = 32; off >= 1; off >>= 1){
      int oc = __shfl_down(bc, off);
      int oi = __shfl_down(bi, off);
      if (oc > bc || (oc == bc && oi < bi)){ bc = oc; bi = oi; }
    }
    if (l == 0){ mc[task] = bc; mi[task] = bi; }
  }
  __syncthreads();
  if (t == 0){
    float dist = 1e8f;
    int best = 0;
    for (int it = 0; it < NITER; ++it){
      int sum = 0;
      for (int b = 0; b < NB; ++b) sum += mc[(it << 3) + b];
      float vv = (float)sum / 16384.0f;
      if (vv < dist){ dist = vv; best = it; }
    }
    best_sh = best;
  }
  __syncthreads();
  int bit = best_sh;
  for (int i = t; i < 96; i += 512){
    float v;
    if (i < 72){
      int bb = i / 9, k = i % 9;
      v = Rt[((size_t)bit*(NB*NS) + (size_t)((bb << 10) + mi[(bit << 3) + bb]))*12 + k];
    } else {
      int ii = i - 72; int bb = ii / 3, k = ii % 3;
      v = Rt[((size_t)bit*(NB*NS) + (size_t)((bb << 10) + mi[(bit << 3) + bb]))*12 + 9 + k];
    }
    out[i] = v;
  }
}

// ---------------- kernel 5b: sequential-path select (fallback) ----------------
__global__ __launch_bounds__(512) void ghv_select_s(const float* __restrict__ Rt,
                                                    const int* __restrict__ fit,
                                                    float* __restrict__ dist_ws,
                                                    float* __restrict__ out,
                                                    int first){
  __shared__ int mc[8], mi[8];
  __shared__ int flag;
  int t = threadIdx.x;
  int b = t >> 6, lane = t & 63;
  int bc = -1, bi = 0;
  for (int s = lane; s < NS; s += 64){
    int c = fit[(b << 10) + s];
    if (c > bc){ bc = c; bi = s; }
  }
  for (int off = 32; off >= 1; off >>= 1){
    int oc = __shfl_down(bc, off);
    int oi = __shfl_down(bi, off);
    if (oc > bc || (oc == bc && oi < bi)){ bc = oc; bi = oi; }
  }
  if (lane == 0){ mc[b] = bc; mi[b] = bi; }
  __syncthreads();
  if (t == 0){
    int sum = 0; for (int i = 0; i < 8; ++i) sum += mc[i];
    float vv = (float)sum / 16384.0f;
    float dist = first ? 1e8f : dist_ws[0];
    int better = (vv < dist) ? 1 : 0;
    if (better) dist_ws[0] = vv;
    flag = better;
  }
  __syncthreads();
  if (flag){
    for (int i = t; i < 96; i += 512){
      float v;
      if (i < 72){
        int bb = i / 9, k = i % 9;
        v = Rt[(size_t)((bb << 10) + mi[bb])*12 + k];
      } else {
        int ii = i - 72; int bb = ii / 3, k = ii % 3;
        v = Rt[(size_t)((bb << 10) + mi[bb])*12 + 9 + k];
      }
      out[i] = v;
    }
  }
}

// ---------------- host ----------------
extern "C" void kernel_launch(void* const* d_in, const int* in_sizes, int n_in,
                              void* d_out, int out_size, void* d_ws, size_t ws_size,
                              hipStream_t stream){
  const float* src = (const float*)d_in[0];
  const float* tgt = (const float*)d_in[1];
  const float* win = (const float*)d_in[2];
  float* out = (float*)d_out;
  char* ws = (char*)d_ws;

  const size_t SEEDS_SZ = (size_t)NB*NS*8*4;     // 262144
  const size_t RT_SZ    = (size_t)NB*NS*12*4;    // 393216
  const size_t NN_SZ    = (size_t)NB*NS*32*2;    // 524288
  const size_t FIT_SZ   = (size_t)NB*NS*4;       // 32768
  const size_t W_SZ     = (size_t)NB*NPTS*4;     // 65536

  size_t off_w    = 0;
  size_t off_logw = off_w + W_SZ;
  size_t off_seed = off_logw + W_SZ;
  size_t off_Rt   = off_seed + NITER*SEEDS_SZ;
  size_t off_nn   = off_Rt + NITER*RT_SZ;
  size_t off_fit  = off_nn + NITER*NN_SZ;
  size_t need_b   = off_fit + NITER*FIT_SZ;

  if (ws_size >= need_b){
    float* w     = (float*)(ws + off_w);
    float* logw  = (float*)(ws + off_logw);
    float* seeds = (float*)(ws + off_seed);
    float* Rt    = (float*)(ws + off_Rt);
    unsigned short* nnb = (unsigned short*)(ws + off_nn);
    int*   fit   = (int*)(ws + off_fit);

    ghv_softmax<<<NB, 256, 0, stream>>>(win, w, logw);
    ghv_seed   <<<dim3(NB, 1, NITER), 1024, 0, stream>>>(src, tgt, w, logw, seeds, 0, 0);
    ghv_nn     <<<dim3(NS, NB, NITER), 512, 0, stream>>>(seeds, nnb, 0, 0);
    ghv_kabsch <<<dim3(NB*NS/64, 1, NITER), 64, 0, stream>>>(seeds, nnb, Rt, 0, 0);
    ghv_fitness<<<dim3(NS/16, NB, NITER), 256, 0, stream>>>(src, tgt, Rt, fit);
    ghv_select_b<<<1, 512, 0, stream>>>(Rt, fit, out);
  } else {
    size_t o_w = 0, o_lw = W_SZ, o_sd = 2*W_SZ, o_rt = o_sd + SEEDS_SZ,
           o_nn2 = o_rt + RT_SZ, o_ft = o_nn2 + NN_SZ, o_ds = o_ft + FIT_SZ;
    float* w     = (float*)(ws + o_w);
    float* logw  = (float*)(ws + o_lw);
    float* seeds = (float*)(ws + o_sd);
    float* Rt    = (float*)(ws + o_rt);
    unsigned short* nnb = (unsigned short*)(ws + o_nn2);
    int*   fit   = (int*)(ws + o_ft);
    float* dist  = (float*)(ws + o_ds);

    ghv_softmax<<<NB, 256, 0, stream>>>(win, w, logw);
    for (int it = 0; it < NITER; ++it){
      ghv_seed   <<<dim3(NB, 1, 1), 1024, 0, stream>>>(src, tgt, w, logw, seeds, it, 1);
      ghv_nn     <<<dim3(NS, NB, 1), 512, 0, stream>>>(seeds, nnb, it, 1);
      ghv_kabsch <<<dim3(NB*NS/64, 1, 1), 64, 0, stream>>>(seeds, nnb, Rt, it, 1);
      ghv_fitness<<<dim3(NS/16, NB, 1), 256, 0, stream>>>(src, tgt, Rt, fit);
      ghv_select_s<<<1, 512, 0, stream>>>(Rt, fit, dist, out, (it == 0) ? 1 : 0);
    }
  }
}